// Round 1
// baseline (240.823 us; speedup 1.0000x reference)
//
#include <hip/hip_runtime.h>
#include <hip/hip_bf16.h>

// Workspace layout:
//   [0, 128)          : float acc[B][4] = {num_pos, cls_sum, reg_sum, dist_sum} (B<=8)
//   [128, 128 + B*A)  : int8 state per anchor: -2 ignore, -1 negative, 0..C-1 positive class

__device__ __forceinline__ float wave_reduce_sum(float v) {
#pragma unroll
    for (int off = 32; off > 0; off >>= 1) v += __shfl_down(v, off);
    return v;
}

__device__ __forceinline__ float smooth_l1(float d) {
    // beta = 1/9: d<=beta ? 0.5*9*d^2 : d - 0.5/9
    return d <= (1.0f / 9.0f) ? 4.5f * d * d : d - (0.5f / 9.0f);
}

__global__ __launch_bounds__(256) void phase1_kernel(
    const float* __restrict__ reg, const float* __restrict__ dist,
    const float* __restrict__ anchors, const float* __restrict__ ann,
    float* __restrict__ acc, signed char* __restrict__ state,
    int A, int C, int M) {
    const int b = blockIdx.y;
    __shared__ float s_ann[64 * 6];
    const float* annb = ann + (size_t)b * M * 6;
    for (int i = threadIdx.x; i < M * 6; i += blockDim.x) s_ann[i] = annb[i];
    __syncthreads();

    const int a = blockIdx.x * blockDim.x + threadIdx.x;
    float l_npos = 0.f, l_reg = 0.f, l_dist = 0.f;
    if (a < A) {
        const float4 av = *(const float4*)(anchors + (size_t)a * 4);
        const float aw = av.z - av.x, ah = av.w - av.y;
        const float acx = av.x + 0.5f * aw, acy = av.y + 0.5f * ah;
        const float aarea = aw * ah;

        float best = -1.0f;
        int bi = 0;
        for (int m = 0; m < M; ++m) {
            const float* g = s_ann + m * 6;
            float iou = -1.0f;
            if (g[4] != -1.0f) {
                float iw = fmaxf(fminf(av.z, g[2]) - fmaxf(av.x, g[0]), 0.f);
                float ih = fmaxf(fminf(av.w, g[3]) - fmaxf(av.y, g[1]), 0.f);
                float inter = iw * ih;
                float area = (g[2] - g[0]) * (g[3] - g[1]);
                float ua = fmaxf(aarea + area - inter, 1e-8f);
                iou = inter / ua;
            }
            if (iou > best) { best = iou; bi = m; }  // strict > => first max (jnp.argmax)
        }

        signed char st;
        if (best >= 0.5f) {
            const float* g = s_ann + bi * 6;
            st = (signed char)(int)g[4];
            l_npos = 1.f;
            // box regression targets
            const float4 rv = *(const float4*)(reg + ((size_t)b * A + a) * 4);
            const float gwr = g[2] - g[0], ghr = g[3] - g[1];
            const float gcx = g[0] + 0.5f * gwr, gcy = g[1] + 0.5f * ghr;
            const float gw = fmaxf(gwr, 1.f), gh = fmaxf(ghr, 1.f);
            const float t0 = ((gcx - acx) / aw) / 0.1f;
            const float t1 = ((gcy - acy) / ah) / 0.1f;
            const float t2 = __logf(gw / aw) / 0.2f;
            const float t3 = __logf(gh / ah) / 0.2f;
            l_reg = smooth_l1(fabsf(t0 - rv.x)) + smooth_l1(fabsf(t1 - rv.y)) +
                    smooth_l1(fabsf(t2 - rv.z)) + smooth_l1(fabsf(t3 - rv.w));
            // distance Huber (delta = 0.5)
            const float dv = dist[(size_t)b * A + a];
            const float dd = fabsf(dv - g[5]);
            l_dist = dd <= 0.5f ? 0.5f * dd * dd : 0.5f * (dd - 0.25f);
        } else if (best < 0.4f) {
            st = -1;
        } else {
            st = -2;
        }
        state[(size_t)b * A + a] = st;
    }

    // block reduce the three partial sums
    __shared__ float s_red[3][4];
    const float w0 = wave_reduce_sum(l_npos);
    const float w1 = wave_reduce_sum(l_reg);
    const float w2 = wave_reduce_sum(l_dist);
    const int lane = threadIdx.x & 63, wid = threadIdx.x >> 6;
    if (lane == 0) { s_red[0][wid] = w0; s_red[1][wid] = w1; s_red[2][wid] = w2; }
    __syncthreads();
    if (threadIdx.x == 0) {
        float t0 = 0.f, t1 = 0.f, t2 = 0.f;
#pragma unroll
        for (int i = 0; i < 4; ++i) { t0 += s_red[0][i]; t1 += s_red[1][i]; t2 += s_red[2][i]; }
        atomicAdd(&acc[b * 4 + 0], t0);
        atomicAdd(&acc[b * 4 + 2], t1);
        atomicAdd(&acc[b * 4 + 3], t2);
    }
}

__global__ __launch_bounds__(256) void phase2_kernel(
    const float* __restrict__ cls, const signed char* __restrict__ state,
    float* __restrict__ acc, int A, int C) {
    const int b = blockIdx.y;
    const int cpa = C >> 2;  // float4 chunks per anchor (C % 4 == 0)
    const float* __restrict__ clsb = cls + (size_t)b * A * C;
    const signed char* __restrict__ stb = state + (size_t)b * A;

    const long long stride = (long long)gridDim.x * blockDim.x;
    const long long idx0 = (long long)blockIdx.x * blockDim.x + threadIdx.x;
    int a = (int)(idx0 / cpa);
    int cc = (int)(idx0 % cpa);
    const int dA = (int)(stride / cpa);
    const int dC = (int)(stride % cpa);

    float lsum = 0.f;
    while (a < A) {
        const int st = stb[a];
        if (st != -2) {
            const int c0 = cc << 2;
            const float4 cv = *(const float4*)(clsb + (size_t)a * C + c0);
#pragma unroll
            for (int j = 0; j < 4; ++j) {
                float c = j == 0 ? cv.x : j == 1 ? cv.y : j == 2 ? cv.z : cv.w;
                c = fminf(fmaxf(c, 1e-4f), 1.0f - 1e-4f);
                const bool ispos = (st == c0 + j);
                const float om = 1.0f - c;
                const float x = ispos ? c : om;                       // log argument
                const float w = ispos ? 0.25f * om * om : 0.75f * c * c;  // focal weight
                lsum -= w * __logf(x);
            }
        }
        a += dA;
        cc += dC;
        if (cc >= cpa) { cc -= cpa; a += 1; }
    }

    const float v = wave_reduce_sum(lsum);
    __shared__ float s_red[4];
    const int lane = threadIdx.x & 63, wid = threadIdx.x >> 6;
    if (lane == 0) s_red[wid] = v;
    __syncthreads();
    if (threadIdx.x == 0) {
        atomicAdd(&acc[b * 4 + 1], s_red[0] + s_red[1] + s_red[2] + s_red[3]);
    }
}

__global__ void finalize_kernel(const float* __restrict__ acc, float* __restrict__ out, int B) {
    if (threadIdx.x == 0) {
        float cs = 0.f, rs = 0.f, ds = 0.f;
        for (int b = 0; b < B; ++b) {
            const float np_ = acc[b * 4 + 0];
            const float denom = fmaxf(np_, 1.f);
            cs += acc[b * 4 + 1] / denom;
            rs += np_ > 0.f ? acc[b * 4 + 2] / (denom * 4.f) : 0.f;
            ds += np_ > 0.f ? acc[b * 4 + 3] / denom : 0.f;
        }
        out[0] = cs / (float)B;
        out[1] = rs / (float)B;
        out[2] = ds / (float)B;
    }
}

extern "C" void kernel_launch(void* const* d_in, const int* in_sizes, int n_in,
                              void* d_out, int out_size, void* d_ws, size_t ws_size,
                              hipStream_t stream) {
    const float* cls     = (const float*)d_in[0];
    const float* reg     = (const float*)d_in[1];
    const float* dist    = (const float*)d_in[2];
    const float* anchors = (const float*)d_in[3];
    const float* ann     = (const float*)d_in[4];

    const int A = in_sizes[3] / 4;
    const int B = in_sizes[1] / (A * 4);
    const int C = in_sizes[0] / (B * A);
    const int M = in_sizes[4] / (B * 6);

    float* acc = (float*)d_ws;
    signed char* state = (signed char*)d_ws + 128;

    hipMemsetAsync(d_ws, 0, 128, stream);

    dim3 b1(256), g1((A + 255) / 256, B);
    phase1_kernel<<<g1, b1, 0, stream>>>(reg, dist, anchors, ann, acc, state, A, C, M);

    dim3 b2(256), g2(1024, B);
    phase2_kernel<<<g2, b2, 0, stream>>>(cls, state, acc, A, C);

    finalize_kernel<<<1, 64, 0, stream>>>(acc, (float*)d_out, B);
}